// Round 6
// baseline (197.910 us; speedup 1.0000x reference)
//
#include <hip/hip_runtime.h>

typedef _Float16 f16;
typedef f16 f16x8 __attribute__((ext_vector_type(8)));
typedef f16 f16x4 __attribute__((ext_vector_type(4)));
typedef __fp16 h16x2 __attribute__((ext_vector_type(2)));   // cvt_pkrtz native type
typedef float f32x4 __attribute__((ext_vector_type(4)));
typedef float f32x2 __attribute__((ext_vector_type(2)));

#define MFMA16(A, B, C) __builtin_amdgcn_mfma_f32_16x16x32_f16((A), (B), (C), 0, 0, 0)

// LDS-only drain (no vmcnt: keeps x prefetch in flight).
#define LGKM_DRAIN() asm volatile("s_waitcnt lgkmcnt(0)" ::: "memory")

__device__ __forceinline__ float E2(float x) {   // 2^x
#if __has_builtin(__builtin_amdgcn_exp2f)
  return __builtin_amdgcn_exp2f(x);
#else
  return __expf(x * 0.69314718056f);
#endif
}

__device__ __forceinline__ f16x8 cvt8(float4 a, float4 b) {
  union { h16x2 h[4]; f16x8 v; } u;
  u.h[0] = __builtin_amdgcn_cvt_pkrtz(a.x, a.y);
  u.h[1] = __builtin_amdgcn_cvt_pkrtz(a.z, a.w);
  u.h[2] = __builtin_amdgcn_cvt_pkrtz(b.x, b.y);
  u.h[3] = __builtin_amdgcn_cvt_pkrtz(b.z, b.w);
  return u.v;
}

// Spin until flags[0] >= thrA && flags[1] >= thrB (one lgkm round per poll).
__device__ __forceinline__ void wait2(volatile int* fl, int thrA, int thrB) {
  while (fl[0] < thrA || fl[1] < thrB) { }
}

// Packed gate math for a pair of h-rows.  float2 ops -> v_pk_*_f32.
// sigmoid pair shares one rcp; tanh(y) = (1-c)*rcp(1+c), c = 2^(-2*log2e*y).
__device__ __forceinline__ void gates_pair(f32x2 aR, f32x2 aZ, f32x2 aXN,
                                           f32x2 aHN, f32x2& hs) {
  const float K = -1.44269504f;  // -log2(e)
  f32x2 mR = aR * K;
  f32x2 mZ = aZ * K;
  f32x2 ea, eb;
  ea[0] = E2(mR[0]); ea[1] = E2(mR[1]);
  eb[0] = E2(mZ[0]); eb[1] = E2(mZ[1]);
  f32x2 pa = ea + 1.0f;
  f32x2 pb = eb + 1.0f;
  f32x2 prod = pa * pb;
  f32x2 inv;
  inv[0] = __builtin_amdgcn_rcpf(prod[0]);
  inv[1] = __builtin_amdgcn_rcpf(prod[1]);
  f32x2 rg = pb * inv;                 // sigmoid(aR)
  f32x2 zg = pa * inv;                 // sigmoid(aZ)
  f32x2 y = rg * aHN + aXN;
  f32x2 my = y * (2.0f * K);           // -2*log2e*y
  f32x2 c;
  c[0] = E2(my[0]); c[1] = E2(my[1]);
  f32x2 num = 1.0f - c;
  f32x2 den = 1.0f + c;
  f32x2 rin;
  rin[0] = __builtin_amdgcn_rcpf(den[0]);
  rin[1] = __builtin_amdgcn_rcpf(den[1]);
  f32x2 ng = num * rin;                // tanh(y)
  hs = zg * (hs - ng) + ng;
}

// B=4096, T=128, D=32, H=64.  16 batch / WG, 8 waves.
// Waves 0-3 (A): layer 0.  Waves 4-7 (B): layer 1, one step behind.
// NO s_barrier in the loop: groups sync via LDS flag counters.
//   flags[0] += 1 per A-wave per completed step; flags[1] likewise for B.
//   A at t:  flagA>=4t (own group wrote h0(t-1)), flagB>=4(t-3) (ring slot free)
//   B at t:  flagA>=4(t+1) (h0(t) ready),        flagB>=4t (own h1(t-1) ready)
// H0 = 4-slot ring (h0(t) in slot t&3), H1 = 2-slot ring (h1(t) in slot t&1).
// Loops unrolled x4 so slots + x-prefetch regs are compile-time (no scratch).
// H layout per slot: h[k] of batch b at f16 offset ((k>>3)*16+b)*8+(k&7)
//   -> B-frag for lane L, kfrag f = stride-1 ds_read_b128 at f*1024 + L*16.
__launch_bounds__(512, 2)
__global__ void gru_fused(const float* __restrict__ x,
                          const float* __restrict__ Wih0, const float* __restrict__ Whh0,
                          const float* __restrict__ bih0, const float* __restrict__ bhh0,
                          const float* __restrict__ Wih1, const float* __restrict__ Whh1,
                          const float* __restrict__ bih1, const float* __restrict__ bhh1,
                          const float* __restrict__ fcw, const float* __restrict__ fcb,
                          float* __restrict__ out) {
  __shared__ f16 H0[4][1024];
  __shared__ f16 H1[2][1024];
  __shared__ float red[4][16];
  __shared__ int flags[2];

  const int tid = threadIdx.x;
  const int wave = tid >> 6;
  const int lane = tid & 63;
  const int l15 = lane & 15;
  const int q = lane >> 4;
  const int wa = wave & 3;
  const bool isB = wave >= 4;
  const int b0 = blockIdx.x * 16;

  // init rings (only slots H0[3], H1[1] must be zero; zero all for safety)
  for (int i = tid; i < 4096; i += 512) ((f16*)H0)[i] = (f16)0.0f;
  for (int i = tid; i < 2048; i += 512) ((f16*)H1)[i] = (f16)0.0f;
  if (tid == 0) { flags[0] = 0; flags[1] = 0; }

  // ---- register-resident weight A-fragments: A[m=l15][k = kf*32 + q*8 + j]
  f16x8 wAx[3];          // layer0 Wih (K=32)       — group A only
  f16x8 wAh[3][2];       // layer0 Whh (K=64)       — group A only
  f16x8 wBx[3][2];       // layer1 Wih (K=64)       — group B only
  f16x8 wBh[3][2];       // layer1 Whh (K=64)       — group B only
  f32x4 bR, bZ, bXN, bHN;
  float fw[4] = {0.f, 0.f, 0.f, 0.f};

  if (!isB) {
#pragma unroll
    for (int g = 0; g < 3; ++g) {
      const int row = g * 64 + 16 * wa + l15;
      const float* p = Wih0 + row * 32 + q * 8;
      wAx[g] = cvt8(*(const float4*)p, *(const float4*)(p + 4));
#pragma unroll
      for (int kf = 0; kf < 2; ++kf) {
        const float* ph = Whh0 + row * 64 + kf * 32 + q * 8;
        wAh[g][kf] = cvt8(*(const float4*)ph, *(const float4*)(ph + 4));
      }
    }
#pragma unroll
    for (int r = 0; r < 4; ++r) {
      const int o = 16 * wa + 4 * q + r;
      bR[r] = bih0[o] + bhh0[o];
      bZ[r] = bih0[64 + o] + bhh0[64 + o];
      bXN[r] = bih0[128 + o];
      bHN[r] = bhh0[128 + o];
    }
  } else {
#pragma unroll
    for (int g = 0; g < 3; ++g) {
      const int row = g * 64 + 16 * wa + l15;
#pragma unroll
      for (int kf = 0; kf < 2; ++kf) {
        const float* p1 = Wih1 + row * 64 + kf * 32 + q * 8;
        wBx[g][kf] = cvt8(*(const float4*)p1, *(const float4*)(p1 + 4));
        const float* p2 = Whh1 + row * 64 + kf * 32 + q * 8;
        wBh[g][kf] = cvt8(*(const float4*)p2, *(const float4*)(p2 + 4));
      }
    }
#pragma unroll
    for (int r = 0; r < 4; ++r) {
      const int o = 16 * wa + 4 * q + r;
      bR[r] = bih1[o] + bhh1[o];
      bZ[r] = bih1[64 + o] + bhh1[64 + o];
      bXN[r] = bih1[128 + o];
      bHN[r] = bhh1[128 + o];
      fw[r] = fcw[o];
    }
  }
  const float fcb0 = fcb[0];

  f32x2 hsA = {0.f, 0.f}, hsB2 = {0.f, 0.f};  // this lane's 4 h rows (own layer)

  const int wk0 = 16 * wa + 4 * q;                          // this lane's 4 h-row indices
  const int widx = ((wk0 >> 3) * 16 + l15) * 8 + (wk0 & 7); // f16 offset of its b64 store

  __syncthreads();   // rings + flags visible to all waves (one-time, full drain ok)

  if (!isB) {
    // ================= group A: layer 0, steps 0..127 =================
    const float* xbase = x + (size_t)(b0 + l15) * 4096 + q * 8;
    float4 xa0 = *(const float4*)(xbase +  0), xb0 = *(const float4*)(xbase +  4);
    float4 xa1 = *(const float4*)(xbase + 32), xb1 = *(const float4*)(xbase + 36);
    float4 xa2 = *(const float4*)(xbase + 64), xb2 = *(const float4*)(xbase + 68);
    float4 xa3 = *(const float4*)(xbase + 96), xb3 = *(const float4*)(xbase + 100);

    auto stepA = [&](int t, const f16* H0r, f16* H0w, float4& pxa, float4& pxb) {
      wait2(flags, 4 * t, 4 * t - 12);
      const f16x8 xf = cvt8(pxa, pxb);
      if (t + 4 < 128) {
        const float* xp = xbase + (t + 4) * 32;
        pxa = *(const float4*)xp;
        pxb = *(const float4*)(xp + 4);
      }
      const f16x8 h0f0 = *(const f16x8*)&H0r[lane * 8];
      const f16x8 h0f1 = *(const f16x8*)&H0r[512 + lane * 8];
      f32x4 aR = bR, aZ = bZ, aXN = bXN, aHN = bHN;
      aR = MFMA16(wAx[0], xf, aR);
      aZ = MFMA16(wAx[1], xf, aZ);
      aR = MFMA16(wAh[0][0], h0f0, aR);
      aZ = MFMA16(wAh[1][0], h0f0, aZ);
      aR = MFMA16(wAh[0][1], h0f1, aR);
      aZ = MFMA16(wAh[1][1], h0f1, aZ);
      aXN = MFMA16(wAx[2], xf, aXN);
      aHN = MFMA16(wAh[2][0], h0f0, aHN);
      aHN = MFMA16(wAh[2][1], h0f1, aHN);
      gates_pair(f32x2{aR[0], aR[1]}, f32x2{aZ[0], aZ[1]},
                 f32x2{aXN[0], aXN[1]}, f32x2{aHN[0], aHN[1]}, hsA);
      gates_pair(f32x2{aR[2], aR[3]}, f32x2{aZ[2], aZ[3]},
                 f32x2{aXN[2], aXN[3]}, f32x2{aHN[2], aHN[3]}, hsB2);
      union { h16x2 h2[2]; f16x4 v; } uw;
      uw.h2[0] = __builtin_amdgcn_cvt_pkrtz(hsA[0], hsA[1]);
      uw.h2[1] = __builtin_amdgcn_cvt_pkrtz(hsB2[0], hsB2[1]);
      *(f16x4*)&H0w[widx] = uw.v;
      LGKM_DRAIN();
      if (lane == 0) atomicAdd(&flags[0], 1);
    };

#pragma unroll 1
    for (int t = 0; t < 128; t += 4) {
      stepA(t,     &H0[3][0], &H0[0][0], xa0, xb0);
      stepA(t + 1, &H0[0][0], &H0[1][0], xa1, xb1);
      stepA(t + 2, &H0[1][0], &H0[2][0], xa2, xb2);
      stepA(t + 3, &H0[2][0], &H0[3][0], xa3, xb3);
    }
  } else {
    // ================= group B: layer 1, steps 0..127 =================
    auto stepB = [&](int t, const f16* H0r, const f16* H1r, f16* H1w) {
      wait2(flags, 4 * t + 4, 4 * t);
      const f16x8 g0 = *(const f16x8*)&H0r[lane * 8];
      const f16x8 g1 = *(const f16x8*)&H0r[512 + lane * 8];
      const f16x8 h1f0 = *(const f16x8*)&H1r[lane * 8];
      const f16x8 h1f1 = *(const f16x8*)&H1r[512 + lane * 8];
      f32x4 aR = bR, aZ = bZ, aXN = bXN, aHN = bHN;
      aR = MFMA16(wBx[0][0], g0, aR);
      aZ = MFMA16(wBx[1][0], g0, aZ);
      aR = MFMA16(wBx[0][1], g1, aR);
      aZ = MFMA16(wBx[1][1], g1, aZ);
      aR = MFMA16(wBh[0][0], h1f0, aR);
      aZ = MFMA16(wBh[1][0], h1f0, aZ);
      aR = MFMA16(wBh[0][1], h1f1, aR);
      aZ = MFMA16(wBh[1][1], h1f1, aZ);
      aXN = MFMA16(wBx[2][0], g0, aXN);
      aXN = MFMA16(wBx[2][1], g1, aXN);
      aHN = MFMA16(wBh[2][0], h1f0, aHN);
      aHN = MFMA16(wBh[2][1], h1f1, aHN);
      gates_pair(f32x2{aR[0], aR[1]}, f32x2{aZ[0], aZ[1]},
                 f32x2{aXN[0], aXN[1]}, f32x2{aHN[0], aHN[1]}, hsA);
      gates_pair(f32x2{aR[2], aR[3]}, f32x2{aZ[2], aZ[3]},
                 f32x2{aXN[2], aXN[3]}, f32x2{aHN[2], aHN[3]}, hsB2);
      union { h16x2 h2[2]; f16x4 v; } uw;
      uw.h2[0] = __builtin_amdgcn_cvt_pkrtz(hsA[0], hsA[1]);
      uw.h2[1] = __builtin_amdgcn_cvt_pkrtz(hsB2[0], hsB2[1]);
      *(f16x4*)&H1w[widx] = uw.v;
      LGKM_DRAIN();
      if (lane == 0) atomicAdd(&flags[1], 1);
    };

#pragma unroll 1
    for (int t = 0; t < 128; t += 4) {
      stepB(t,     &H0[0][0], &H1[1][0], &H1[0][0]);
      stepB(t + 1, &H0[1][0], &H1[0][0], &H1[1][0]);
      stepB(t + 2, &H0[2][0], &H1[1][0], &H1[0][0]);
      stepB(t + 3, &H0[3][0], &H1[0][0], &H1[1][0]);
    }

    // fc partial: out[b] = sum_i h1[i]*fcw[i] + fcb  (B holds h1(127))
    float partial = fw[0] * hsA[0] + fw[1] * hsA[1] + fw[2] * hsB2[0] + fw[3] * hsB2[1];
    partial += __shfl_down(partial, 16, 64);
    partial += __shfl_down(partial, 32, 64);
    if (lane < 16) red[wa][l15] = partial;
  }

  __syncthreads();
  if (tid < 16) out[b0 + tid] = red[0][tid] + red[1][tid] + red[2][tid] + red[3][tid] + fcb0;
}

extern "C" void kernel_launch(void* const* d_in, const int* in_sizes, int n_in,
                              void* d_out, int out_size, void* d_ws, size_t ws_size,
                              hipStream_t stream) {
  (void)in_sizes; (void)n_in; (void)out_size; (void)d_ws; (void)ws_size;
  const float* x    = (const float*)d_in[0];
  const float* Wih0 = (const float*)d_in[1];
  const float* Whh0 = (const float*)d_in[2];
  const float* bih0 = (const float*)d_in[3];
  const float* bhh0 = (const float*)d_in[4];
  const float* Wih1 = (const float*)d_in[5];
  const float* Whh1 = (const float*)d_in[6];
  const float* bih1 = (const float*)d_in[7];
  const float* bhh1 = (const float*)d_in[8];
  const float* fcw  = (const float*)d_in[9];
  const float* fcb  = (const float*)d_in[10];
  float* out = (float*)d_out;

  gru_fused<<<256, 512, 0, stream>>>(x, Wih0, Whh0, bih0, bhh0,
                                     Wih1, Whh1, bih1, bhh1, fcw, fcb, out);
}

// Round 7
// 177.172 us; speedup vs baseline: 1.1170x; 1.1170x over previous
//
#include <hip/hip_runtime.h>

typedef _Float16 f16;
typedef f16 f16x8 __attribute__((ext_vector_type(8)));
typedef f16 f16x4 __attribute__((ext_vector_type(4)));
typedef __fp16 h16x2 __attribute__((ext_vector_type(2)));   // cvt_pkrtz native type
typedef float f32x4 __attribute__((ext_vector_type(4)));
typedef float f32x2 __attribute__((ext_vector_type(2)));

#define MFMA16(A, B, C) __builtin_amdgcn_mfma_f32_16x16x32_f16((A), (B), (C), 0, 0, 0)

// Barrier WITHOUT vmcnt drain: only LDS (lgkmcnt) must be visible across it.
// __syncthreads() emits s_waitcnt vmcnt(0) and would serialize the in-flight
// x prefetch into the critical path every iteration.  (R6 showed LDS flag
// sync is WORSE than s_barrier: +400 cyc/step handoff latency.)
#define LDS_BARRIER() asm volatile("s_waitcnt lgkmcnt(0)\n\ts_barrier" ::: "memory")

__device__ __forceinline__ float E2(float x) {   // 2^x
#if __has_builtin(__builtin_amdgcn_exp2f)
  return __builtin_amdgcn_exp2f(x);
#else
  return __expf(x * 0.69314718056f);
#endif
}

__device__ __forceinline__ f16x8 cvt8(float4 a, float4 b) {
  union { h16x2 h[4]; f16x8 v; } u;
  u.h[0] = __builtin_amdgcn_cvt_pkrtz(a.x, a.y);
  u.h[1] = __builtin_amdgcn_cvt_pkrtz(a.z, a.w);
  u.h[2] = __builtin_amdgcn_cvt_pkrtz(b.x, b.y);
  u.h[3] = __builtin_amdgcn_cvt_pkrtz(b.z, b.w);
  return u.v;
}

// Packed gate math for a pair of h-rows.  float2 ops -> v_pk_*_f32.
// sigmoid pair shares one rcp; tanh(y) = (1-c)*rcp(1+c), c = 2^(-2*log2e*y).
// Proven correct in R6 (absmax 3.9e-3).
__device__ __forceinline__ void gates_pair(f32x2 aR, f32x2 aZ, f32x2 aXN,
                                           f32x2 aHN, f32x2& hs) {
  const float K = -1.44269504f;  // -log2(e)
  f32x2 mR = aR * K;
  f32x2 mZ = aZ * K;
  f32x2 ea, eb;
  ea[0] = E2(mR[0]); ea[1] = E2(mR[1]);
  eb[0] = E2(mZ[0]); eb[1] = E2(mZ[1]);
  f32x2 pa = ea + 1.0f;
  f32x2 pb = eb + 1.0f;
  f32x2 prod = pa * pb;
  f32x2 inv;
  inv[0] = __builtin_amdgcn_rcpf(prod[0]);
  inv[1] = __builtin_amdgcn_rcpf(prod[1]);
  f32x2 rg = pb * inv;                 // sigmoid(aR)
  f32x2 zg = pa * inv;                 // sigmoid(aZ)
  f32x2 y = rg * aHN + aXN;
  f32x2 my = y * (2.0f * K);           // -2*log2e*y
  f32x2 c;
  c[0] = E2(my[0]); c[1] = E2(my[1]);
  f32x2 num = 1.0f - c;
  f32x2 den = 1.0f + c;
  f32x2 rin;
  rin[0] = __builtin_amdgcn_rcpf(den[0]);
  rin[1] = __builtin_amdgcn_rcpf(den[1]);
  f32x2 ng = num * rin;                // tanh(y)
  hs = zg * (hs - ng) + ng;
}

// B=4096, T=128, D=32, H=64.  16 batch / WG, 8 waves.
// Waves 0-3 (group A): layer 0, step t.   Waves 4-7 (group B): layer 1, step t-1.
// Time loop unrolled x2 so the ping-pong parity and prefetch slots are
// compile-time constants (R4: runtime-indexed arrays -> scratch).  One
// LDS-only s_barrier per pipeline step (R5 structure, best known).
// Wave wa owns gate rows [16wa,16wa+16) of r/z/n; A-operand = weights
// (register resident), B-operand = x / h fragments.
// H LDS layout: h[k] for batch b at f16 offset ((k>>3)*16+b)*8 + (k&7)
//   -> B-frag for lane L, kfrag f = stride-1 ds_read_b128 at f*1024 + L*16.
__launch_bounds__(512, 2)
__global__ void gru_fused(const float* __restrict__ x,
                          const float* __restrict__ Wih0, const float* __restrict__ Whh0,
                          const float* __restrict__ bih0, const float* __restrict__ bhh0,
                          const float* __restrict__ Wih1, const float* __restrict__ Whh1,
                          const float* __restrict__ bih1, const float* __restrict__ bhh1,
                          const float* __restrict__ fcw, const float* __restrict__ fcb,
                          float* __restrict__ out) {
  __shared__ f16 H0[2][1024];
  __shared__ f16 H1[2][1024];
  __shared__ float red[4][16];

  const int tid = threadIdx.x;
  const int wave = tid >> 6;
  const int lane = tid & 63;
  const int l15 = lane & 15;
  const int q = lane >> 4;
  const int wa = wave & 3;
  const bool isB = wave >= 4;
  const int b0 = blockIdx.x * 16;

  for (int i = tid; i < 2048; i += 512) {
    ((f16*)H0)[i] = (f16)0.0f;
    ((f16*)H1)[i] = (f16)0.0f;
  }

  // ---- register-resident weight A-fragments: A[m=l15][k = kf*32 + q*8 + j]
  f16x8 wAx[3];          // layer0 Wih (K=32)       — group A only
  f16x8 wAh[3][2];       // layer0 Whh (K=64)       — group A only
  f16x8 wBx[3][2];       // layer1 Wih (K=64)       — group B only
  f16x8 wBh[3][2];       // layer1 Whh (K=64)       — group B only
  f32x4 bR, bZ, bXN, bHN;
  float fw[4] = {0.f, 0.f, 0.f, 0.f};

  if (!isB) {
#pragma unroll
    for (int g = 0; g < 3; ++g) {
      const int row = g * 64 + 16 * wa + l15;
      const float* p = Wih0 + row * 32 + q * 8;
      wAx[g] = cvt8(*(const float4*)p, *(const float4*)(p + 4));
#pragma unroll
      for (int kf = 0; kf < 2; ++kf) {
        const float* ph = Whh0 + row * 64 + kf * 32 + q * 8;
        wAh[g][kf] = cvt8(*(const float4*)ph, *(const float4*)(ph + 4));
      }
    }
#pragma unroll
    for (int r = 0; r < 4; ++r) {
      const int o = 16 * wa + 4 * q + r;
      bR[r] = bih0[o] + bhh0[o];
      bZ[r] = bih0[64 + o] + bhh0[64 + o];
      bXN[r] = bih0[128 + o];
      bHN[r] = bhh0[128 + o];
    }
  } else {
#pragma unroll
    for (int g = 0; g < 3; ++g) {
      const int row = g * 64 + 16 * wa + l15;
#pragma unroll
      for (int kf = 0; kf < 2; ++kf) {
        const float* p1 = Wih1 + row * 64 + kf * 32 + q * 8;
        wBx[g][kf] = cvt8(*(const float4*)p1, *(const float4*)(p1 + 4));
        const float* p2 = Whh1 + row * 64 + kf * 32 + q * 8;
        wBh[g][kf] = cvt8(*(const float4*)p2, *(const float4*)(p2 + 4));
      }
    }
#pragma unroll
    for (int r = 0; r < 4; ++r) {
      const int o = 16 * wa + 4 * q + r;
      bR[r] = bih1[o] + bhh1[o];
      bZ[r] = bih1[64 + o] + bhh1[64 + o];
      bXN[r] = bih1[128 + o];
      bHN[r] = bhh1[128 + o];
      fw[r] = fcw[o];
    }
  }
  const float fcb0 = fcb[0];

  f32x2 hs01 = {0.f, 0.f}, hs23 = {0.f, 0.f};  // this lane's 4 h rows (own layer)

  const int wk0 = 16 * wa + 4 * q;                          // this lane's 4 h-row indices
  const int widx = ((wk0 >> 3) * 16 + l15) * 8 + (wk0 & 7); // f16 offset of its b64 store

  // layer-0 step: read H0r, consume x frag, write H0w
  auto stepA = [&](const f16* H0r, f16* H0w, float4 xav, float4 xbv) {
    const f16x8 xf = cvt8(xav, xbv);
    const f16x8 h0f0 = *(const f16x8*)&H0r[lane * 8];
    const f16x8 h0f1 = *(const f16x8*)&H0r[512 + lane * 8];
    f32x4 aR = bR, aZ = bZ, aXN = bXN, aHN = bHN;
    aR = MFMA16(wAx[0], xf, aR);
    aZ = MFMA16(wAx[1], xf, aZ);
    aXN = MFMA16(wAx[2], xf, aXN);
    aR = MFMA16(wAh[0][0], h0f0, aR);
    aZ = MFMA16(wAh[1][0], h0f0, aZ);
    aHN = MFMA16(wAh[2][0], h0f0, aHN);
    aR = MFMA16(wAh[0][1], h0f1, aR);
    aZ = MFMA16(wAh[1][1], h0f1, aZ);
    aHN = MFMA16(wAh[2][1], h0f1, aHN);
    gates_pair(f32x2{aR[0], aR[1]}, f32x2{aZ[0], aZ[1]},
               f32x2{aXN[0], aXN[1]}, f32x2{aHN[0], aHN[1]}, hs01);
    gates_pair(f32x2{aR[2], aR[3]}, f32x2{aZ[2], aZ[3]},
               f32x2{aXN[2], aXN[3]}, f32x2{aHN[2], aHN[3]}, hs23);
    union { h16x2 h2[2]; f16x4 v; } uw;
    uw.h2[0] = __builtin_amdgcn_cvt_pkrtz(hs01[0], hs01[1]);
    uw.h2[1] = __builtin_amdgcn_cvt_pkrtz(hs23[0], hs23[1]);
    *(f16x4*)&H0w[widx] = uw.v;
  };

  // layer-1 step: read h0 from H0r, own state from H1r, write H1w
  auto stepB = [&](const f16* H0r, const f16* H1r, f16* H1w) {
    const f16x8 g0 = *(const f16x8*)&H0r[lane * 8];
    const f16x8 g1 = *(const f16x8*)&H0r[512 + lane * 8];
    const f16x8 h1f0 = *(const f16x8*)&H1r[lane * 8];
    const f16x8 h1f1 = *(const f16x8*)&H1r[512 + lane * 8];
    f32x4 aR = bR, aZ = bZ, aXN = bXN, aHN = bHN;
    aR = MFMA16(wBx[0][0], g0, aR);
    aZ = MFMA16(wBx[1][0], g0, aZ);
    aXN = MFMA16(wBx[2][0], g0, aXN);
    aR = MFMA16(wBx[0][1], g1, aR);
    aZ = MFMA16(wBx[1][1], g1, aZ);
    aXN = MFMA16(wBx[2][1], g1, aXN);
    aR = MFMA16(wBh[0][0], h1f0, aR);
    aZ = MFMA16(wBh[1][0], h1f0, aZ);
    aHN = MFMA16(wBh[2][0], h1f0, aHN);
    aR = MFMA16(wBh[0][1], h1f1, aR);
    aZ = MFMA16(wBh[1][1], h1f1, aZ);
    aHN = MFMA16(wBh[2][1], h1f1, aHN);
    gates_pair(f32x2{aR[0], aR[1]}, f32x2{aZ[0], aZ[1]},
               f32x2{aXN[0], aXN[1]}, f32x2{aHN[0], aHN[1]}, hs01);
    gates_pair(f32x2{aR[2], aR[3]}, f32x2{aZ[2], aZ[3]},
               f32x2{aXN[2], aXN[3]}, f32x2{aHN[2], aHN[3]}, hs23);
    union { h16x2 h2[2]; f16x4 v; } uw;
    uw.h2[0] = __builtin_amdgcn_cvt_pkrtz(hs01[0], hs01[1]);
    uw.h2[1] = __builtin_amdgcn_cvt_pkrtz(hs23[0], hs23[1]);
    *(f16x4*)&H1w[widx] = uw.v;
  };

  __syncthreads();

  // x B-frag source (group A only): lane (l15,q) reads x[b0+l15][t][q*8..q*8+7]
  // 2-deep prefetch in STATICALLY NAMED registers (slot0 = even t, slot1 = odd).
  const float* xbase = x + (size_t)(b0 + l15) * 4096 + q * 8;
  float4 xa0, xb0, xa1, xb1;
  if (!isB) {
    xa0 = *(const float4*)xbase;
    xb0 = *(const float4*)(xbase + 4);
    xa1 = *(const float4*)(xbase + 32);
    xb1 = *(const float4*)(xbase + 36);
  }

  for (int t = 0; t < 128; t += 2) {
    // ---- pipeline iteration t (parity 0): A step t, B step t-1
    if (!isB) {
      const float4 cxa = xa0, cxb = xb0;
      if (t + 2 < 128) {
        const float* xp = xbase + (t + 2) * 32;
        xa0 = *(const float4*)xp;
        xb0 = *(const float4*)(xp + 4);
      }
      stepA(H0[0], H0[1], cxa, cxb);
    } else if (t > 0) {
      stepB(H0[0], H1[0], H1[1]);
    }
    LDS_BARRIER();

    // ---- pipeline iteration t+1 (parity 1): A step t+1, B step t
    if (!isB) {
      const float4 cxa = xa1, cxb = xb1;
      if (t + 3 < 128) {
        const float* xp = xbase + (t + 3) * 32;
        xa1 = *(const float4*)xp;
        xb1 = *(const float4*)(xp + 4);
      }
      stepA(H0[1], H0[0], cxa, cxb);
    } else {
      stepB(H0[1], H1[1], H1[0]);
    }
    LDS_BARRIER();
  }
  // ---- pipeline iteration t=128 (parity 0): B step 127 only
  if (isB) stepB(H0[0], H1[0], H1[1]);

  // ---- fc: out[b] = sum_i h1[i]*fcw[i] + fcb   (group B holds h1(127))
  if (isB) {
    float partial = fw[0] * hs01[0] + fw[1] * hs01[1] + fw[2] * hs23[0] + fw[3] * hs23[1];
    partial += __shfl_down(partial, 16, 64);
    partial += __shfl_down(partial, 32, 64);
    if (lane < 16) red[wa][l15] = partial;
  }
  __syncthreads();
  if (tid < 16) out[b0 + tid] = red[0][tid] + red[1][tid] + red[2][tid] + red[3][tid] + fcb0;
}

extern "C" void kernel_launch(void* const* d_in, const int* in_sizes, int n_in,
                              void* d_out, int out_size, void* d_ws, size_t ws_size,
                              hipStream_t stream) {
  (void)in_sizes; (void)n_in; (void)out_size; (void)d_ws; (void)ws_size;
  const float* x    = (const float*)d_in[0];
  const float* Wih0 = (const float*)d_in[1];
  const float* Whh0 = (const float*)d_in[2];
  const float* bih0 = (const float*)d_in[3];
  const float* bhh0 = (const float*)d_in[4];
  const float* Wih1 = (const float*)d_in[5];
  const float* Whh1 = (const float*)d_in[6];
  const float* bih1 = (const float*)d_in[7];
  const float* bhh1 = (const float*)d_in[8];
  const float* fcw  = (const float*)d_in[9];
  const float* fcb  = (const float*)d_in[10];
  float* out = (float*)d_out;

  gru_fused<<<256, 512, 0, stream>>>(x, Wih0, Whh0, bih0, bhh0,
                                     Wih1, Whh1, bih1, bhh1, fcw, fcb, out);
}